// Round 4
// baseline (285.133 us; speedup 1.0000x reference)
//
#include <hip/hip_runtime.h>
#include <math.h>

#define N_SYM 128
#define BATCH 131072
#define LEV   30.0f
#define RING  4               // LDS ring slots (groups of 4 symbols)
#define NGRP  (N_SYM / 4)     // 32 groups

typedef float v4 __attribute__((ext_vector_type(4)));

// R6: wave-autonomous cooperative staging, ZERO barriers.
// Evidence ledger:
//   R0-R2: dword/lane, 8 free waves/CU -> 6.8 GB/s/CU (request-rate cap on
//          256 B reqs). R3: v4 VGPR ring, 2 free waves/CU -> 10.4 GB/s/CU,
//          ring depth D=4==D=8 (null). R4/R5: barrier-locked P/C and
//          coop variants, 2-8 waves/CU -> 7.0-7.4 GB/s/CU (barrier kills
//          overlap). m13 copy: many free v4 waves -> 24.6 GB/s/CU.
// Model: free-running wave ~= 1 req / 200 ns regardless of size/depth;
// CU reaches ~1 KB / 40 ns with >=8 FREE-RUNNING v4-issuing waves.
// Design: 1 wave/block, 64 cols/wave, 2048 blocks = 8 blocks/CU.
//   - per 4-symbol group: 4x global_load_lds dwordx4 (1 KB each), LDS
//     lands linear [arr][sym][col]; counted vmcnt (steady 15, never 0).
//   - each lane computes ONE column (um in VGPR) from stride-1 LDS reads.
//   - outputs gathered via 1 KB LDS bounce -> ONE dwordx4 store per group
//     (store stream also 1 KB requests; requests budget = BW budget).
//   - intra-wave lockstep replaces every barrier; no s_barrier in kernel.
__device__ __forceinline__ void gload16(const float* g, float* l)
{
    __builtin_amdgcn_global_load_lds(
        (const __attribute__((address_space(1))) void*)g,
        (__attribute__((address_space(3))) void*)l,
        16, 0, 0);
}

__device__ __forceinline__ float step1(float f, float e, float p, float m,
                                       float st, float mn, float mx,
                                       float* um)
{
    const float mrl = m * LEV;
    const float us  = *um * mrl;                // unused_size
    const float mps = fabsf(p) + us;            // max_pos_size
    const float adj = fminf((p * f > 0.0f) ? us : mps, 0.0f);
    const float nps = f * (mps - adj);

    float       a  = fabsf(nps);
    const float sg = copysignf(1.0f, nps);
    a = floorf(a / st) * st;
    a = (a < mn) ? 0.0f : a;
    a = fminf(a, mx);

    *um = (mps - a) / mrl;
    return e * (sg * a) + (1.0f - e) * p;
}

#define VMWAIT(N) asm volatile("s_waitcnt vmcnt(" #N ")" ::: "memory")

__global__ __launch_bounds__(64) void lle_wave_kernel(
    const float* __restrict__ frac,
    const float* __restrict__ exs,
    const float* __restrict__ pos,
    const float* __restrict__ mrate,
    const float* __restrict__ um0,
    const float* __restrict__ msm_min,
    const float* __restrict__ msm_step,
    const float* __restrict__ msm_max,
    float* __restrict__ out)
{
    // [slot][arr f/e/p/m][sym-in-group][col] = 4*4*4*64*4 B = 16 KiB
    __shared__ __align__(16) float lin[RING][4][4][64];
    __shared__ __align__(16) float lout[4][64];          // 1 KiB bounce

    const int l       = threadIdx.x;        // single wave per block
    const int colbase = blockIdx.x * 64;

    const float* srcs[4] = { frac, exs, pos, mrate };

    // lane l fetches symbol (g*4 + (l>>4)), cols 4*(l&15).. of each array;
    // LDS dest is wave-uniform base + lane*16 -> linear [sym][col] layout.
    const size_t lrow = (size_t)(l >> 4);
    const size_t lcol = (size_t)colbase + 4 * (l & 15);

    auto issue = [&](int g) {
        const int slot = g & (RING - 1);
        const size_t row = (size_t)g * 4 + lrow;
#pragma unroll
        for (int A = 0; A < 4; ++A)
            gload16(srcs[A] + row * BATCH + lcol, &lin[slot][A][0][0]);
    };

    float um = um0[colbase + l];

    auto consume = [&](int g) {
        const int slot = g & (RING - 1);
#pragma unroll
        for (int j = 0; j < 4; ++j) {
            const int   s  = g * 4 + j;
            const float st = msm_step[s];   // uniform -> s_load
            const float mn = msm_min[s];
            const float mx = msm_max[s];
            const float f  = lin[slot][0][j][l];
            const float e  = lin[slot][1][j][l];
            const float pv = lin[slot][2][j][l];
            const float m  = lin[slot][3][j][l];
            lout[j][l] = step1(f, e, pv, m, st, mn, mx, &um);
        }
        // gather 4 dword-columns -> one 1 KB dwordx4 store per wave
        const v4 ro = *(const v4*)&lout[l >> 4][4 * (l & 15)];
        __builtin_nontemporal_store(
            ro, (v4*)(out + ((size_t)g * 4 + lrow) * BATCH + lcol));
    };

    // ---- software pipeline, counted vmcnt, no barriers ----
    // vmem issue order: L0 L1 L2 | L3 S0 | L4 S1 | L5 S2 | L6 S3 | ...
    // steady: newer-than-L(g) = 3 stores + 12 loads = 15.
    issue(0); issue(1); issue(2);

    issue(3); VMWAIT(12); consume(0);
    issue(4); VMWAIT(12); consume(1);   // exact=13; 12 is safe
    issue(5); VMWAIT(12); consume(2);   // exact=14; 12 is safe

    for (int g = 3; g <= NGRP - 4; ++g) {
        issue(g + 3);
        VMWAIT(15);
        consume(g);
    }

    VMWAIT(11); consume(NGRP - 3);      // newer = 2S + 8L + 1S = 11
    VMWAIT(7);  consume(NGRP - 2);      // newer = 3S + 4L      = 7
    VMWAIT(3);  consume(NGRP - 1);      // newer = 3S           = 3

    // final unused_margin row (dword/lane; 2048 tiny reqs total, negligible)
    __builtin_nontemporal_store(um, &out[(size_t)N_SYM * BATCH + colbase + l]);
}

extern "C" void kernel_launch(void* const* d_in, const int* in_sizes, int n_in,
                              void* d_out, int out_size, void* d_ws, size_t ws_size,
                              hipStream_t stream) {
    const float* frac     = (const float*)d_in[0];
    const float* exs      = (const float*)d_in[1];
    const float* pos      = (const float*)d_in[2];
    const float* mrate    = (const float*)d_in[3];
    const float* um0      = (const float*)d_in[4];
    const float* msm_min  = (const float*)d_in[5];
    const float* msm_step = (const float*)d_in[6];
    const float* msm_max  = (const float*)d_in[7];
    float* out = (float*)d_out;

    const int block = 64;            // ONE wave per block, fully autonomous
    const int grid  = BATCH / 64;    // 2048 blocks -> 8 blocks/CU

    hipLaunchKernelGGL(lle_wave_kernel, dim3(grid), dim3(block), 0, stream,
                       frac, exs, pos, mrate, um0, msm_min, msm_step, msm_max,
                       out);
}

// Round 7
// 266.471 us; speedup vs baseline: 1.0700x; 1.0700x over previous
//
#include <hip/hip_runtime.h>
#include <math.h>

#define N_SYM 128
#define BATCH 131072
#define LEV   30.0f
#define G     4                 // symbols per phase
#define NPH   (N_SYM / G)       // 32 phases
#define CPB   256               // columns per block (1 per thread)

typedef float v4 __attribute__((ext_vector_type(4)));

// R9 = R8 resubmitted (de-lambda'd). Two "container failed twice" rounds
// carry no kernel-level diagnostics; ISA-level audit finds no hang (waits
// are upper-bound waits; uniform control flow -> matched barrier counts)
// and no fault (all accesses bounds-audited; row-128 um store proven by
// R3/R6 passing). Infra history (push_in_npz_s 905-1420 s rounds 1-3,
// fast only when preloaded) says input-push timeout kills the container
// before the kernel runs. Design under test -- the last untried cell:
//   8 waves/CU x VGPR dwordx4 loads. Model (fits R0-R6 + m13):
//   CU VMEM service ~1 req/40ns; per-wave ~1 req/100-200ns;
//   global_load_lds path ~4x slower (closed by R4/R5/R6).
//   -> 2 waves/CU (R3) wave-capped at 10.4 GB/s/CU; 8 waves of 1 KB
//   requests should hit the CU cap ~25 GB/s/CU => ~50 us.
// Structure: 512 blocks x 256 thr (4 waves), 1 column/thread compute.
//   wave w loads array w as 4x dwordx4/phase -> 3-phase VGPR ring
//   (12 loads in flight), ds_write 2-slot staging, raw s_barrier +
//   hand-counted vmcnt (never 0 mid-loop; stores always younger than
//   any waited load). Output bounced via lout -> wave w gather-stores
//   symbol w as ONE dwordx4. sched_barrier(0) pins VMEM issue order so
//   the vmcnt ledger is enforceable (guide rule #18).
__device__ __forceinline__ float step1(float f, float e, float p, float m,
                                       float st, float mn, float mx,
                                       float* um)
{
    const float mrl = m * LEV;
    const float us  = *um * mrl;                // unused_size
    const float mps = fabsf(p) + us;            // max_pos_size
    const float adj = fminf((p * f > 0.0f) ? us : mps, 0.0f);
    const float nps = f * (mps - adj);

    float       a  = fabsf(nps);
    const float sg = copysignf(1.0f, nps);
    a = floorf(a / st) * st;
    a = (a < mn) ? 0.0f : a;
    a = fminf(a, mx);

    *um = (mps - a) / mrl;
    return e * (sg * a) + (1.0f - e) * p;
}

#define VMWAIT(N) asm volatile("s_waitcnt vmcnt(" #N ")" ::: "memory")
#define LGKM0()   asm volatile("s_waitcnt lgkmcnt(0)" ::: "memory")
#define SCHED0()  __builtin_amdgcn_sched_barrier(0)
#define BAR()     do { __builtin_amdgcn_s_barrier(); \
                       asm volatile("" ::: "memory"); } while (0)

// load phase PG of this wave's array into 4 v4 regs
#define LOADPH(PG, DST)                                                    \
    do {                                                                   \
        _Pragma("unroll")                                                  \
        for (int _j = 0; _j < G; ++_j)                                     \
            (DST)[_j] = *(const v4*)(mysrc +                               \
                        (size_t)((PG) * G + _j) * BATCH + gcol);           \
        SCHED0();                                                          \
    } while (0)

// stage 4 v4 regs into LDS slot SL (this wave's array row)
#define STAGE(SL, SRC)                                                     \
    do {                                                                   \
        _Pragma("unroll")                                                  \
        for (int _j = 0; _j < G; ++_j)                                     \
            *(v4*)&stg[SL][_j][wave][4 * lane] = (SRC)[_j];                \
    } while (0)

// per-thread column recurrence over staged phase PG
#define CONSUME(PG)                                                        \
    do {                                                                   \
        const int _sl = (PG) & 1;                                          \
        _Pragma("unroll")                                                  \
        for (int _j = 0; _j < G; ++_j) {                                   \
            const int   _s  = (PG) * G + _j;                               \
            const float _st = msm_step[_s];                                \
            const float _mn = msm_min[_s];                                 \
            const float _mx = msm_max[_s];                                 \
            const float _f  = stg[_sl][_j][0][t];                          \
            const float _e  = stg[_sl][_j][1][t];                          \
            const float _pv = stg[_sl][_j][2][t];                          \
            const float _m  = stg[_sl][_j][3][t];                          \
            lout[_j][t] = step1(_f, _e, _pv, _m, _st, _mn, _mx, &um);      \
        }                                                                  \
    } while (0)

// wave w gather-stores symbol w of phase PG as one dwordx4
#define GSTORE(PG)                                                         \
    do {                                                                   \
        const v4 _rv = *(const v4*)&lout[wave][4 * lane];                  \
        __builtin_nontemporal_store(_rv,                                   \
            (v4*)(out + (size_t)((PG) * G + wave) * BATCH + gcol));        \
        SCHED0();                                                          \
    } while (0)

#define ROT3()                                                             \
    do {                                                                   \
        _Pragma("unroll")                                                  \
        for (int _j = 0; _j < G; ++_j) { rA[_j] = rB[_j]; rB[_j] = rC[_j]; } \
    } while (0)

__global__ __launch_bounds__(256) void lle_xchg_kernel(
    const float* __restrict__ frac,
    const float* __restrict__ exs,
    const float* __restrict__ pos,
    const float* __restrict__ mrate,
    const float* __restrict__ um0,
    const float* __restrict__ msm_min,
    const float* __restrict__ msm_step,
    const float* __restrict__ msm_max,
    float* __restrict__ out)
{
    __shared__ __align__(16) float stg[2][G][4][CPB];   // 32 KiB staging
    __shared__ __align__(16) float lout[G][CPB];        // 4 KiB out-bounce

    const int t    = threadIdx.x;
    const int wave = t >> 6;
    const int lane = t & 63;
    const int C0   = blockIdx.x * CPB;

    const float* mysrc = (wave == 0) ? frac : (wave == 1) ? exs
                       : (wave == 2) ? pos  : mrate;
    const size_t gcol = (size_t)C0 + 4 * (size_t)lane;  // this lane's 4 cols

    float um = um0[C0 + t];

    v4 t0[G], rA[G], rB[G], rC[G];

    // ---- prologue: L0->t0, L1->rA, L2->rB (12 loads in flight) ----
    LOADPH(0, t0);
    LOADPH(1, rA);
    LOADPH(2, rB);
    VMWAIT(8); SCHED0();       // L0 arrived (8 younger: L1,L2)
    STAGE(0, t0);
    LGKM0(); BAR();            // slot0 visible

    // ---- phase 0 (peeled: wait counts differ) ----
    CONSUME(0);
    LGKM0(); BAR();            // lout visible; slot0 free
    GSTORE(0);                                   // vmem: 1S
    VMWAIT(5); SCHED0();       // rA=L1 arrived (younger: L2 4L + 1S)
    STAGE(1, rA);
    LOADPH(3, rC);                               // vmem: 4L
    ROT3();
    LGKM0(); BAR();            // slot1 visible

    // ---- steady phases 1..28 ----
    // queue at GSTORE(g): [L(g+1) maybe-done, S(g-1), L(g+2), S(g), L(g+3)]
    // after GSTORE: +S(g); VMWAIT(6) retires through L(g+1):
    //   younger = S(g-1)+4L+S(g) = 6. Never drains to 0.
#pragma unroll 1
    for (int g = 1; g <= 28; ++g) {
        CONSUME(g);
        LGKM0(); BAR();
        GSTORE(g);                               // 1S
        VMWAIT(6); SCHED0();
        STAGE((g + 1) & 1, rA);
        LOADPH(g + 3, rC);                       // 4L
        ROT3();
        LGKM0(); BAR();
    }

    // ---- phase 29: no more prefetch ----
    CONSUME(29);
    LGKM0(); BAR();
    GSTORE(29);                                  // 1S
    VMWAIT(6); SCHED0();       // rA=L30: younger = 1S(28)+4L(31)+1S(29)
    STAGE(0, rA);              // (29+1)&1 = 0
#pragma unroll
    for (int j = 0; j < G; ++j) rA[j] = rB[j];   // rA = L31
    LGKM0(); BAR();

    // ---- phase 30 ----
    CONSUME(30);
    LGKM0(); BAR();
    GSTORE(30);                                  // 1S
    VMWAIT(2); SCHED0();       // rA=L31: younger = 1S(29)+1S(30)
    STAGE(1, rA);              // (30+1)&1 = 1
    LGKM0(); BAR();

    // ---- phase 31 ----
    CONSUME(31);
    LGKM0(); BAR();
    GSTORE(31);

    // final unused_margin row (1 dword/thread; negligible request count)
    __builtin_nontemporal_store(um, &out[(size_t)N_SYM * BATCH + C0 + t]);
}

extern "C" void kernel_launch(void* const* d_in, const int* in_sizes, int n_in,
                              void* d_out, int out_size, void* d_ws, size_t ws_size,
                              hipStream_t stream) {
    const float* frac     = (const float*)d_in[0];
    const float* exs      = (const float*)d_in[1];
    const float* pos      = (const float*)d_in[2];
    const float* mrate    = (const float*)d_in[3];
    const float* um0      = (const float*)d_in[4];
    const float* msm_min  = (const float*)d_in[5];
    const float* msm_step = (const float*)d_in[6];
    const float* msm_max  = (const float*)d_in[7];
    float* out = (float*)d_out;

    const int block = 256;           // 4 waves: one per input array
    const int grid  = BATCH / CPB;   // 512 blocks -> 2/CU, 8 waves/CU

    hipLaunchKernelGGL(lle_xchg_kernel, dim3(grid), dim3(block), 0, stream,
                       frac, exs, pos, mrate, um0, msm_min, msm_step, msm_max,
                       out);
}